// Round 1
// baseline (305.587 us; speedup 1.0000x reference)
//
#include <hip/hip_runtime.h>
#include <stdint.h>

// NeiAttention: B=512, N=32, S=16, EF=64, NF=D=128, K=192
// v3: 8-wave blocks, 2 tiles/iter, wave-per-col-tile (24 VGPR W frags),
//     shfl alpha reduce (no lds_ap, 3 barriers / 2 tiles), one-pass softmax.
//     Target: VGPR <= 64 -> 8 waves/SIMD -> 32 waves/CU (2x occupancy).

typedef __attribute__((ext_vector_type(8))) short short8;
typedef __attribute__((ext_vector_type(4))) float float4_t;
typedef __attribute__((ext_vector_type(4))) unsigned short ushort4_t;

#define GRID_ 1024
#define ITERS_ 8   // 1024 blocks * 8 iters * 2 tiles = 16384 = B*N

__device__ __forceinline__ unsigned short f2bf(float f) {
    uint32_t u = __float_as_uint(f);
    u += 0x7fffu + ((u >> 16) & 1u);   // RNE
    return (unsigned short)(u >> 16);
}

// A-fragment-packed LDS offset (ushort units) for element (s, k):
// kstep q = k/32, quad = (k%32)/8, j = k%8; owner lane = quad*16 + s.
__device__ __forceinline__ int aoff(int s, int kc) {
    return (((kc >> 5) * 64) + (((kc & 31) >> 3) * 16) + s) * 8 + (kc & 7);
}

__global__ __launch_bounds__(512, 8) void nei_attn_kernel(
    const float* __restrict__ x,
    const float* __restrict__ rel,
    const float* __restrict__ node,
    const float* __restrict__ W,
    const float* __restrict__ bias,
    float* __restrict__ out)
{
    __shared__ __align__(16) unsigned short lds_a[2][6 * 64 * 8]; // 12 KB bf16 A-frags
    __shared__ float lds_x[2][128];
    __shared__ float lds_v[2][16 * 132];                          // stride 132: <=2-way
    __shared__ float lds_alpha[2][16];

    const int t    = threadIdx.x;
    const int tl   = t & 255;       // thread within half
    const int h    = t >> 8;        // half = tile within iteration
    const int lane = t & 63;
    const int wv   = t >> 6;        // wave 0..7 = output column tile
    const int l15  = lane & 15;
    const int quad = (lane >> 4) & 3;

    // ---- W^T B-fragments + bias: wave wv owns cols wv*16..wv*16+15 ----
    // 6 short8 = 24 VGPRs (was 48 with 2 col-tiles/wave).
    short8 bf[6];
    const int row = wv * 16 + l15;         // output dim d
    const float bias_c = bias[row];
    #pragma unroll
    for (int q = 0; q < 6; ++q) {
        const float* p = W + row * 192 + q * 32 + quad * 8;
        float4_t a0 = *(const float4_t*)p;
        float4_t a1 = *(const float4_t*)(p + 4);
        short8 f;
        f[0] = (short)f2bf(a0.x); f[1] = (short)f2bf(a0.y);
        f[2] = (short)f2bf(a0.z); f[3] = (short)f2bf(a0.w);
        f[4] = (short)f2bf(a1.x); f[5] = (short)f2bf(a1.y);
        f[6] = (short)f2bf(a1.z); f[7] = (short)f2bf(a1.w);
        bf[q] = f;
    }

    // Staging map per half (768 float4 per tile over 256 threads, 3 each):
    //   c=0: rel   f4 #tl       -> (s = tl>>4,     k = (tl&15)*4)
    //   c=1: node  f4 #tl       -> (s = tl>>5,     k = 64 + (tl&31)*4)
    //   c=2: node  f4 #(tl+256) -> (s = 8+(tl>>5), k = 64 + (tl&31)*4)
    const int s0 = tl >> 4,  kc0 = (tl & 15) << 2;
    const int s1 = tl >> 5,  kc1 = 64 + ((tl & 31) << 2);
    const int s2 = s1 + 8;
    const int ao0 = h * 3072 + aoff(s0, kc0);
    const int ao1 = h * 3072 + aoff(s1, kc1);
    const int ao2 = h * 3072 + aoff(s2, kc1);
    unsigned short* la = &lds_a[0][0];

    int idx = blockIdx.x * (ITERS_ * 2);

    // ---- prefetch iteration 0 (x as a single scalar across 256 threads) ----
    float4_t pf0, pf1, pf2;
    float pfx = 0.f;
    {
        const float* pr = rel  + (idx + h) * 1024;   // 16*64 floats per (b,n)
        const float* pn = node + (idx + h) * 2048;   // 16*128 floats per (b,n)
        pf0 = *(const float4_t*)(pr + tl * 4);
        pf1 = *(const float4_t*)(pn + tl * 4);
        pf2 = *(const float4_t*)(pn + 1024 + tl * 4);
        if (t < 256) pfx = x[(idx + (t >> 7)) * 128 + (t & 127)];
    }

    for (int it = 0; it < ITERS_; ++it) {
        // ---- stage regs -> LDS (bf16, A-fragment packed) ----
        {
            ushort4_t u;
            u[0] = f2bf(pf0.x); u[1] = f2bf(pf0.y); u[2] = f2bf(pf0.z); u[3] = f2bf(pf0.w);
            *(ushort4_t*)&la[ao0] = u;
            u[0] = f2bf(pf1.x); u[1] = f2bf(pf1.y); u[2] = f2bf(pf1.z); u[3] = f2bf(pf1.w);
            *(ushort4_t*)&la[ao1] = u;
            u[0] = f2bf(pf2.x); u[1] = f2bf(pf2.y); u[2] = f2bf(pf2.z); u[3] = f2bf(pf2.w);
            *(ushort4_t*)&la[ao2] = u;
            if (t < 256) lds_x[t >> 7][t & 127] = pfx;
        }
        __syncthreads();   // (1) lds_a / lds_x ready

        // ---- prefetch next iteration (latency hidden under MFMA+attention) ----
        if (it + 1 < ITERS_) {
            const int nidx = idx + 2;
            const float* pr = rel  + (nidx + h) * 1024;
            const float* pn = node + (nidx + h) * 2048;
            pf0 = *(const float4_t*)(pr + tl * 4);
            pf1 = *(const float4_t*)(pn + tl * 4);
            pf2 = *(const float4_t*)(pn + 1024 + tl * 4);
            if (t < 256) pfx = x[(nidx + (t >> 7)) * 128 + (t & 127)];
        }

        // ---- projection: wave wv computes cols wv*16.. for BOTH tiles ----
        float4_t acc0 = {0.f, 0.f, 0.f, 0.f};
        float4_t acc1 = {0.f, 0.f, 0.f, 0.f};
        #pragma unroll
        for (int q = 0; q < 6; ++q) {
            short8 af0 = *(const short8*)&la[(q * 64 + lane) * 8];
            short8 af1 = *(const short8*)&la[3072 + (q * 64 + lane) * 8];
            acc0 = __builtin_amdgcn_mfma_f32_16x16x32_bf16(af0, bf[q], acc0, 0, 0, 0);
            acc1 = __builtin_amdgcn_mfma_f32_16x16x32_bf16(af1, bf[q], acc1, 0, 0, 0);
        }
        // C/D layout: lane holds D[quad*4+r][l15]
        const int colw = wv * 16 + l15;
        const int rb = quad * 4;
        #pragma unroll
        for (int r = 0; r < 4; ++r) {
            lds_v[0][(rb + r) * 132 + colw] = acc0[r] + bias_c;
            lds_v[1][(rb + r) * 132 + colw] = acc1[r] + bias_c;
        }
        __syncthreads();   // (2) lds_v ready

        // ---- alpha: thread (h, s=tl>>4, dA=tl&15) sums 8 strided d,
        //      then 16-lane shfl_xor reduce (no lds_ap, no extra barrier) ----
        {
            const int sA = tl >> 4, dA = tl & 15;
            float p = 0.f;
            #pragma unroll
            for (int j = 0; j < 8; ++j) {
                const int d = dA + (j << 4);
                p += lds_x[h][d] * lds_v[h][sA * 132 + d];
            }
            p += __shfl_xor(p, 8);
            p += __shfl_xor(p, 4);
            p += __shfl_xor(p, 2);
            p += __shfl_xor(p, 1);
            if (dA == 0) lds_alpha[h][sA] = p * 0.08838834764831845f; // 1/sqrt(128)
        }
        __syncthreads();   // (3)

        // ---- softmax + weighted sum, ONE pass (no e[16] array) ----
        if (tl < 128) {
            const float* al = lds_alpha[h];
            float m = al[0];
            #pragma unroll
            for (int s = 1; s < 16; ++s) m = fmaxf(m, al[s]);
            float den = 0.f, o = 0.f;
            #pragma unroll
            for (int s = 0; s < 16; ++s) {
                const float e = __expf(al[s] - m);
                den += e;
                o += e * lds_v[h][s * 132 + tl];
            }
            out[(idx + h) * 128 + tl] = o / den;
        }
        idx += 2;
        // no trailing barrier: next-iter stage writes touch lds_a/lds_x only,
        // whose readers all retired before barriers (2)/(3) of this iteration.
    }
}

extern "C" void kernel_launch(void* const* d_in, const int* in_sizes, int n_in,
                              void* d_out, int out_size, void* d_ws, size_t ws_size,
                              hipStream_t stream) {
    const float* x    = (const float*)d_in[0];
    const float* rel  = (const float*)d_in[1];
    const float* node = (const float*)d_in[2];
    const float* W    = (const float*)d_in[3];
    const float* bias = (const float*)d_in[4];
    float* out = (float*)d_out;
    hipLaunchKernelGGL(nei_attn_kernel, dim3(GRID_), dim3(512), 0, stream,
                       x, rel, node, W, bias, out);
}

// Round 2
// 285.850 us; speedup vs baseline: 1.0690x; 1.0690x over previous
//
#include <hip/hip_runtime.h>
#include <stdint.h>

// NeiAttention: B=512, N=32, S=16, EF=64, NF=D=128, K=192
// v4: fix R1 spill regression. 512-thread / 8-wave blocks, wave-per-col-tile.
//     NO software prefetch (12 fewer live VGPRs across compute -> fits 64-reg
//     cap at 8 waves/SIMD; TLP from 4 blocks/CU hides HBM latency instead).
//     + XOR-swizzled A-frag staging (8..16-way -> <=4-way write conflicts)
//     + contiguous-chunk alpha partials (b128 reads, fewer conflicts).

typedef __attribute__((ext_vector_type(8))) short short8;
typedef __attribute__((ext_vector_type(4))) float float4_t;
typedef __attribute__((ext_vector_type(4))) unsigned short ushort4_t;

#define GRID_ 1024
#define ITERS_ 8   // 1024 blocks * 8 iters * 2 tiles = 16384 = B*N

__device__ __forceinline__ unsigned short f2bf(float f) {
    uint32_t u = __float_as_uint(f);
    u += 0x7fffu + ((u >> 16) & 1u);   // RNE
    return (unsigned short)(u >> 16);
}

// Swizzled A-frag LDS offset (ushort units) for element (s, k):
// owner slot X = (k/32)*64 + ((k%32)/8)*16 + s; low 3 bits of X are XORed
// with a hash of the high bits so the 8B staging writes spread across banks.
// Fragment reads (ds_read_b128) apply the identical swizzle and stay
// conflict-free (permutation is within aligned 8-slot groups).
__device__ __forceinline__ int aoff(int s, int kc) {
    int X = ((kc >> 5) << 6) + (((kc & 31) >> 3) << 4) + s;
    X ^= ((X >> 3) ^ (X >> 6)) & 7;
    return X * 8 + (kc & 7);
}

__global__ __launch_bounds__(512, 8) void nei_attn_kernel(
    const float* __restrict__ x,
    const float* __restrict__ rel,
    const float* __restrict__ node,
    const float* __restrict__ W,
    const float* __restrict__ bias,
    float* __restrict__ out)
{
    __shared__ __align__(16) unsigned short lds_a[2][6 * 64 * 8]; // 12 KB bf16 A-frags
    __shared__ float lds_x[2][128];
    __shared__ float lds_v[2][16 * 132];                          // stride 132
    __shared__ float lds_alpha[2][16];

    const int t    = threadIdx.x;
    const int tl   = t & 255;       // thread within half
    const int h    = t >> 8;        // half = tile within iteration
    const int lane = t & 63;
    const int wv   = t >> 6;        // wave 0..7 = output column tile
    const int l15  = lane & 15;
    const int quad = (lane >> 4) & 3;

    // ---- W^T B-fragments + bias: wave wv owns cols wv*16..wv*16+15 ----
    short8 bf[6];
    const int row = wv * 16 + l15;         // output dim d
    const float bias_c = bias[row];
    #pragma unroll
    for (int q = 0; q < 6; ++q) {
        const float* p = W + row * 192 + q * 32 + quad * 8;
        float4_t a0 = *(const float4_t*)p;
        float4_t a1 = *(const float4_t*)(p + 4);
        short8 f;
        f[0] = (short)f2bf(a0.x); f[1] = (short)f2bf(a0.y);
        f[2] = (short)f2bf(a0.z); f[3] = (short)f2bf(a0.w);
        f[4] = (short)f2bf(a1.x); f[5] = (short)f2bf(a1.y);
        f[6] = (short)f2bf(a1.z); f[7] = (short)f2bf(a1.w);
        bf[q] = f;
    }

    // Staging map per half (768 float4 per tile over 256 threads, 3 each):
    //   c=0: rel   f4 #tl       -> (s = tl>>4,     k = (tl&15)*4)
    //   c=1: node  f4 #tl       -> (s = tl>>5,     k = 64 + (tl&31)*4)
    //   c=2: node  f4 #(tl+256) -> (s = 8+(tl>>5), k = 64 + (tl&31)*4)
    const int s0 = tl >> 4,  kc0 = (tl & 15) << 2;
    const int s1 = tl >> 5,  kc1 = 64 + ((tl & 31) << 2);
    const int s2 = s1 + 8;
    const int ao0 = h * 3072 + aoff(s0, kc0);
    const int ao1 = h * 3072 + aoff(s1, kc1);
    const int ao2 = h * 3072 + aoff(s2, kc1);
    // MFMA read-side swizzle helper: owner slot for fragment read is
    // lane ^ ((lane>>3)&7) ^ q  (low-3-bit XOR only; q < 8).
    const int lx = lane ^ ((lane >> 3) & 7);
    unsigned short* la = &lds_a[0][0];

    int idx = blockIdx.x * (ITERS_ * 2);

    #pragma unroll 1
    for (int it = 0; it < ITERS_; ++it) {
        // ---- load (no prefetch; TLP hides latency), convert, stage ----
        {
            const float* pr = rel  + (idx + h) * 1024;   // 16*64 floats per (b,n)
            const float* pn = node + (idx + h) * 2048;   // 16*128 floats per (b,n)
            float4_t pf0 = *(const float4_t*)(pr + tl * 4);
            float4_t pf1 = *(const float4_t*)(pn + tl * 4);
            float4_t pf2 = *(const float4_t*)(pn + 1024 + tl * 4);
            ushort4_t u;
            u[0] = f2bf(pf0.x); u[1] = f2bf(pf0.y); u[2] = f2bf(pf0.z); u[3] = f2bf(pf0.w);
            *(ushort4_t*)&la[ao0] = u;
            u[0] = f2bf(pf1.x); u[1] = f2bf(pf1.y); u[2] = f2bf(pf1.z); u[3] = f2bf(pf1.w);
            *(ushort4_t*)&la[ao1] = u;
            u[0] = f2bf(pf2.x); u[1] = f2bf(pf2.y); u[2] = f2bf(pf2.z); u[3] = f2bf(pf2.w);
            *(ushort4_t*)&la[ao2] = u;
            if (t < 256) lds_x[t >> 7][t & 127] = x[(idx + (t >> 7)) * 128 + (t & 127)];
        }
        __syncthreads();   // (1) lds_a / lds_x ready

        // ---- projection: wave wv computes cols wv*16.. for BOTH tiles ----
        float4_t acc0 = {0.f, 0.f, 0.f, 0.f};
        float4_t acc1 = {0.f, 0.f, 0.f, 0.f};
        #pragma unroll
        for (int q = 0; q < 6; ++q) {
            short8 af0 = *(const short8*)&la[(q * 64 + (lx ^ q)) * 8];
            short8 af1 = *(const short8*)&la[3072 + (q * 64 + (lx ^ q)) * 8];
            acc0 = __builtin_amdgcn_mfma_f32_16x16x32_bf16(af0, bf[q], acc0, 0, 0, 0);
            acc1 = __builtin_amdgcn_mfma_f32_16x16x32_bf16(af1, bf[q], acc1, 0, 0, 0);
        }
        // C/D layout: lane holds D[quad*4+r][l15]
        const int colw = wv * 16 + l15;
        const int rb = quad * 4;
        #pragma unroll
        for (int r = 0; r < 4; ++r) {
            lds_v[0][(rb + r) * 132 + colw] = acc0[r] + bias_c;
            lds_v[1][(rb + r) * 132 + colw] = acc1[r] + bias_c;
        }
        __syncthreads();   // (2) lds_v ready

        // ---- alpha: thread (h, s=tl>>4, dA=tl&15) sums contiguous 8 d,
        //      then 16-lane shfl_xor reduce ----
        {
            const int sA = tl >> 4, dA = tl & 15;
            const float* vx = &lds_x[h][dA * 8];
            const float* vv = &lds_v[h][sA * 132 + dA * 8];
            float p = 0.f;
            #pragma unroll
            for (int j = 0; j < 8; ++j) p += vx[j] * vv[j];
            p += __shfl_xor(p, 8);
            p += __shfl_xor(p, 4);
            p += __shfl_xor(p, 2);
            p += __shfl_xor(p, 1);
            if (dA == 0) lds_alpha[h][sA] = p * 0.08838834764831845f; // 1/sqrt(128)
        }
        __syncthreads();   // (3)

        // ---- softmax + weighted sum, one pass ----
        if (tl < 128) {
            const float* al = lds_alpha[h];
            float m = al[0];
            #pragma unroll
            for (int s = 1; s < 16; ++s) m = fmaxf(m, al[s]);
            float den = 0.f, o = 0.f;
            #pragma unroll
            for (int s = 0; s < 16; ++s) {
                const float e = __expf(al[s] - m);
                den += e;
                o += e * lds_v[h][s * 132 + tl];
            }
            out[(idx + h) * 128 + tl] = o / den;
        }
        idx += 2;
        // no trailing barrier: next-iter stage writes touch lds_a/lds_x only,
        // whose readers all retired before barriers (2)/(3) of this iteration.
    }
}

extern "C" void kernel_launch(void* const* d_in, const int* in_sizes, int n_in,
                              void* d_out, int out_size, void* d_ws, size_t ws_size,
                              hipStream_t stream) {
    const float* x    = (const float*)d_in[0];
    const float* rel  = (const float*)d_in[1];
    const float* node = (const float*)d_in[2];
    const float* W    = (const float*)d_in[3];
    const float* bias = (const float*)d_in[4];
    float* out = (float*)d_out;
    hipLaunchKernelGGL(nei_attn_kernel, dim3(GRID_), dim3(512), 0, stream,
                       x, rel, node, W, bias, out);
}